// Round 9
// baseline (372.325 us; speedup 1.0000x reference)
//
#include <hip/hip_runtime.h>
#include <hip/hip_bf16.h>
#include <stdint.h>

// B=2, N=2048, D=1024, H=8, DH=128.  Inputs fp32, OUTPUT FP32 (proven by
// round-8 probe: bf16 -20480 at byte offset 0 read back as ~0 => harness
// reads 4-byte elements; doc "else float*" was right all along).
// Displayed reference is the oracle:
//   qkv = x@w_qkv^T + b ; reshape (b,n,3,dh,h) -> head INNERMOST:
//   col = kk*1024 + dd*8 + hh ; attn = q k^T (no softmax) ;
//   out_h = attn v == q (k^T v) ; concat 'b h n d -> b n (h d)' ; @w_o^T.
// Pipeline: fp32->bf16 convert, MFMA GEMM -> QKV slabs, M = K^T V (vector),
// O = Q M (vector), MFMA GEMM -> fp32 out. MFMA stages carry an on-device
// sampled fp32-dot check + gated vector fallback.

typedef __bf16 bf16_t;
typedef __bf16 bf16x4 __attribute__((ext_vector_type(4)));
typedef __bf16 bf16x8 __attribute__((ext_vector_type(8)));
typedef float  fx4    __attribute__((ext_vector_type(4)));

typedef const void __attribute__((address_space(1)))* gas_ptr;
typedef void __attribute__((address_space(3)))*       las_ptr;

__device__ __forceinline__ void gl_lds16(const void* g, void* l) {
  __builtin_amdgcn_global_load_lds((gas_ptr)g, (las_ptr)l, 16, 0, 0);
}

#define SLAB 262144   // 2048*128 elems per (q/k/v, b, h) slab

// ---------------------------------------------------------------------------
__global__ __launch_bounds__(256) void beacon_kernel(float* out, float val, int n)
{
  const int i = blockIdx.x * 256 + threadIdx.x;
  if (i < n) out[i] = val;
}

__global__ __launch_bounds__(64) void init_flags_kernel(int* flags)
{
  if (threadIdx.x < 8) flags[threadIdx.x] = 0;
}

// fp32 -> bf16, 4 elems/thread
__global__ __launch_bounds__(256) void conv_kernel(
    const float* __restrict__ src, bf16_t* __restrict__ dst, int n4)
{
  const int i = blockIdx.x * 256 + threadIdx.x;
  if (i >= n4) return;
  const float4 v = ((const float4*)src)[i];
  bf16x4 o;
  o[0] = (bf16_t)v.x; o[1] = (bf16_t)v.y; o[2] = (bf16_t)v.z; o[3] = (bf16_t)v.w;
  ((bf16x4*)dst)[i] = o;
}

// ---------------------------------------------------------------------------
// MFMA GEMM (m97): C[M,N] = A[M,1024] @ Bt[N,1024]^T + bias.
// mode 0: N=3072, scatter QKV slabs, displayed decode (k d h).
// mode 1: N=1024, row-major FP32 out.
// ---------------------------------------------------------------------------
__global__ __launch_bounds__(256) void mfma_gemm_kernel(
    const bf16_t* __restrict__ A, const bf16_t* __restrict__ Bt,
    const float* __restrict__ bias, bf16_t* __restrict__ slab_out,
    float* __restrict__ final_out, int mode)
{
  __shared__ __align__(16) short As[128*32];
  __shared__ __align__(16) short Bs[128*32];
  const int t    = threadIdx.x;
  const int lane = t & 63;
  const int w    = t >> 6;
  const int wr   = (w >> 1) << 6;
  const int wc   = (w & 1) << 6;
  const int lrow = lane & 15;
  const int kq   = (lane >> 4) << 3;
  const int row0 = blockIdx.y * 128;
  const int col0 = blockIdx.x * 128;

  const int i0 = t, i1 = t + 256;
  const bf16_t* a0 = A  + (size_t)(row0 + (i0 >> 2)) * 1024 + ((i0 & 3) << 3);
  const bf16_t* a1 = A  + (size_t)(row0 + (i1 >> 2)) * 1024 + ((i1 & 3) << 3);
  const bf16_t* b0 = Bt + (size_t)(col0 + (i0 >> 2)) * 1024 + ((i0 & 3) << 3);
  const bf16_t* b1 = Bt + (size_t)(col0 + (i1 >> 2)) * 1024 + ((i1 & 3) << 3);
  short* sa0 = &As[i0 * 8]; short* sa1 = &As[i1 * 8];
  short* sb0 = &Bs[i0 * 8]; short* sb1 = &Bs[i1 * 8];

  fx4 acc[4][4] = {};

  for (int k0 = 0; k0 < 1024; k0 += 32) {
    gl_lds16(a0 + k0, sa0);
    gl_lds16(a1 + k0, sa1);
    gl_lds16(b0 + k0, sb0);
    gl_lds16(b1 + k0, sb1);
    __syncthreads();
    bf16x8 af[4], bfr[4];
#pragma unroll
    for (int i = 0; i < 4; ++i)
      af[i] = *(const bf16x8*)&As[(wr + i*16 + lrow)*32 + kq];
#pragma unroll
    for (int j = 0; j < 4; ++j)
      bfr[j] = *(const bf16x8*)&Bs[(wc + j*16 + lrow)*32 + kq];
#pragma unroll
    for (int i = 0; i < 4; ++i)
#pragma unroll
      for (int j = 0; j < 4; ++j)
        acc[i][j] = __builtin_amdgcn_mfma_f32_16x16x32_bf16(af[i], bfr[j], acc[i][j], 0, 0, 0);
    __syncthreads();
  }

  // C/D: col = lane&15, row = (lane>>4)*4 + reg  [m89-verified]
#pragma unroll
  for (int j = 0; j < 4; ++j) {
    const int col = col0 + wc + j*16 + lrow;
    const float bv = bias[col];
#pragma unroll
    for (int i = 0; i < 4; ++i) {
#pragma unroll
      for (int r = 0; r < 4; ++r) {
        const int row = row0 + wr + i*16 + ((lane >> 4) << 2) + r;
        const float v = acc[i][j][r] + bv;
        if (mode == 0) {
          const int kk2 = col >> 10, rem = col & 1023;
          const int dd = rem >> 3, hh = rem & 7;        // displayed (k d h)
          const int bb = row >> 11, nn = row & 2047;
          slab_out[(size_t)(kk2*16 + bb*8 + hh)*SLAB + (size_t)nn*128 + dd] = (bf16_t)v;
        } else {
          final_out[(size_t)row * 1024 + col] = v;      // FP32 store
        }
      }
    }
  }
}

// ---------------------------------------------------------------------------
// Sampled check of mode-0 GEMM (512 samples) vs fp32 dot from same buffers.
__global__ __launch_bounds__(256) void chk1_kernel(
    const bf16_t* __restrict__ xb, const bf16_t* __restrict__ wqkvb,
    const float* __restrict__ bqf, const bf16_t* __restrict__ slabs,
    int* __restrict__ flag)
{
  const int s = blockIdx.x * 256 + threadIdx.x;     // 512
  const unsigned rr = (unsigned)s * 2654435761u;
  const int row = (rr >> 2) & 4095;
  const int col = (int)((rr >> 16) % 3072u);
  float ref = bqf[col];
  const bf16_t* ar = xb    + (size_t)row * 1024;
  const bf16_t* br = wqkvb + (size_t)col * 1024;
  for (int c = 0; c < 1024; c += 8) {
    const bf16x8 a = *(const bf16x8*)(ar + c);
    const bf16x8 b = *(const bf16x8*)(br + c);
#pragma unroll
    for (int j = 0; j < 8; ++j) ref += (float)a[j] * (float)b[j];
  }
  const int kk2 = col >> 10, rem = col & 1023;
  const int dd = rem >> 3, hh = rem & 7;              // displayed (k d h)
  const int bb = row >> 11, nn = row & 2047;
  const float gpu = (float)slabs[(size_t)(kk2*16 + bb*8 + hh)*SLAB + (size_t)nn*128 + dd];
  if (fabsf(gpu - ref) > 0.02f * fabsf(ref) + 0.05f) atomicOr(flag, 1);
}

// Sampled check of mode-1 GEMM (256 samples) on the fp32 final output.
__global__ __launch_bounds__(256) void chk2_kernel(
    const bf16_t* __restrict__ O, const bf16_t* __restrict__ wob,
    const float* __restrict__ bof, const float* __restrict__ outp,
    int* __restrict__ flag)
{
  const int s = threadIdx.x;                        // 256
  const unsigned rr = (unsigned)(s + 7) * 2654435761u;
  const int row = (rr >> 2) & 4095;
  const int col = (rr >> 16) & 1023;
  float ref = bof[col];
  const bf16_t* ar = O   + (size_t)row * 1024;
  const bf16_t* br = wob + (size_t)col * 1024;
  for (int c = 0; c < 1024; c += 8) {
    const bf16x8 a = *(const bf16x8*)(ar + c);
    const bf16x8 b = *(const bf16x8*)(br + c);
#pragma unroll
    for (int j = 0; j < 8; ++j) ref += (float)a[j] * (float)b[j];
  }
  const float gpu = outp[(size_t)row * 1024 + col];
  if (fabsf(gpu - ref) > 0.02f * fabsf(ref) + 1.0f) atomicOr(flag, 1);
}

// ---------------------------------------------------------------------------
// Gated vector fallback GEMM. Runs only if *flag != 0; same math/mapping.
// ---------------------------------------------------------------------------
__global__ __launch_bounds__(256) void vec_gemm_kernel(
    const bf16_t* __restrict__ A, const bf16_t* __restrict__ Bt,
    const float* __restrict__ bias, bf16_t* __restrict__ slab_out,
    float* __restrict__ final_out, int mode, const int* __restrict__ flag)
{
  if (*flag == 0) return;
  __shared__ float As[128 * 17];
  __shared__ float Bs[128 * 17];
  const int t = threadIdx.x;
  const int row0 = blockIdx.y * 128, col0 = blockIdx.x * 128;
  const int sr = t >> 1, skb = (t & 1) * 8;
  const int tr = t >> 4, tc = t & 15;
  float acc[8][8] = {};

  for (int k0 = 0; k0 < 1024; k0 += 16) {
    {
      const bf16x8 v = *(const bf16x8*)(A + (size_t)(row0 + sr) * 1024 + k0 + skb);
      float* d = &As[sr * 17 + skb];
#pragma unroll
      for (int i = 0; i < 8; ++i) d[i] = (float)v[i];
    }
    {
      const bf16x8 v = *(const bf16x8*)(Bt + (size_t)(col0 + sr) * 1024 + k0 + skb);
      float* d = &Bs[sr * 17 + skb];
#pragma unroll
      for (int i = 0; i < 8; ++i) d[i] = (float)v[i];
    }
    __syncthreads();
#pragma unroll
    for (int kk = 0; kk < 16; ++kk) {
      float a[8], b[8];
#pragma unroll
      for (int i = 0; i < 8; ++i) a[i] = As[(tr * 8 + i) * 17 + kk];
#pragma unroll
      for (int j = 0; j < 8; ++j) b[j] = Bs[(tc * 8 + j) * 17 + kk];
#pragma unroll
      for (int i = 0; i < 8; ++i)
#pragma unroll
        for (int j = 0; j < 8; ++j) acc[i][j] += a[i] * b[j];
    }
    __syncthreads();
  }

#pragma unroll
  for (int i = 0; i < 8; ++i) {
    const int row = row0 + tr * 8 + i;
    const int bb = row >> 11, nn = row & 2047;
#pragma unroll
    for (int j = 0; j < 8; ++j) {
      const int col = col0 + tc * 8 + j;
      const float v = acc[i][j] + bias[col];
      if (mode == 0) {
        const int kk2 = col >> 10, rem = col & 1023;
        const int dd = rem >> 3, hh = rem & 7;          // displayed (k d h)
        slab_out[(size_t)(kk2*16 + bb*8 + hh)*SLAB + (size_t)nn*128 + dd] = (bf16_t)v;
      } else {
        final_out[(size_t)row * 1024 + col] = v;        // FP32 store
      }
    }
  }
}

// ---------------------------------------------------------------------------
// Mpart[bh][ch][e][d] = sum_{n in chunk} K[b,h,n,e] * V[b,h,n,d]
__global__ __launch_bounds__(256) void kv_part(
    const bf16_t* __restrict__ slabs, float* __restrict__ Mpart)
{
  __shared__ short Ks[64 * 128];
  __shared__ short Vs[64 * 128];
  const int t = threadIdx.x;
  const int ch = blockIdx.x, bh = blockIdx.y;
  const bf16_t* Kg = slabs + (size_t)(16 + bh) * SLAB;
  const bf16_t* Vg = slabs + (size_t)(32 + bh) * SLAB;
  const int e0 = (t >> 4) * 8, d0 = (t & 15) * 8;
  float acc[8][8] = {};
  for (int sub = 0; sub < 8; ++sub) {
    const int n0 = ch * 512 + sub * 64;
#pragma unroll
    for (int p = 0; p < 4; ++p) {
      const int idx = t + p * 256;
      const int r = idx >> 4, c = (idx & 15) * 8;
      *(uint4*)&Ks[idx * 8] = *(const uint4*)(Kg + (size_t)(n0 + r) * 128 + c);
      *(uint4*)&Vs[idx * 8] = *(const uint4*)(Vg + (size_t)(n0 + r) * 128 + c);
    }
    __syncthreads();
    for (int n = 0; n < 64; ++n) {
      const bf16x8 k8 = *(const bf16x8*)&Ks[n * 128 + e0];
      const bf16x8 v8 = *(const bf16x8*)&Vs[n * 128 + d0];
      float kf[8], vf[8];
#pragma unroll
      for (int i = 0; i < 8; ++i) { kf[i] = (float)k8[i]; vf[i] = (float)v8[i]; }
#pragma unroll
      for (int i = 0; i < 8; ++i)
#pragma unroll
        for (int j = 0; j < 8; ++j) acc[i][j] += kf[i] * vf[j];
    }
    __syncthreads();
  }
  float* op = Mpart + ((size_t)(bh * 4 + ch) << 14);
#pragma unroll
  for (int i = 0; i < 8; ++i)
#pragma unroll
    for (int j = 0; j < 8; ++j)
      op[(e0 + i) * 128 + d0 + j] = acc[i][j];
}

__global__ __launch_bounds__(256) void reduce_m(
    const float* __restrict__ Mpart, float* __restrict__ M)
{
  const int o = blockIdx.x * 256 + threadIdx.x;   // < 262144
  const int bh = o >> 14, rest = o & 16383;
  const float* p = Mpart + ((size_t)(bh * 4) << 14) + rest;
  M[o] = p[0] + p[16384] + p[32768] + p[49152];
}

// O[b*2048+n][h*128+d] = sum_e Q[b,h,n,e] * M[bh][e][d]  (O stays bf16)
__global__ __launch_bounds__(256) void qm(
    const bf16_t* __restrict__ slabs, const float* __restrict__ M,
    bf16_t* __restrict__ O)
{
  __shared__ short Qs[64 * 128];
  __shared__ short Ms[128 * 128];
  const int t = threadIdx.x;
  const int bh = blockIdx.y, n0 = blockIdx.x * 64;
  const int b = bh >> 3, h = bh & 7;
  const bf16_t* Qg = slabs + (size_t)bh * SLAB + (size_t)n0 * 128;
#pragma unroll
  for (int p = 0; p < 4; ++p) {
    const int idx = t + p * 256;
    *(uint4*)&Qs[idx * 8] = *(const uint4*)(Qg + (size_t)idx * 8);
  }
  const float* Mg = M + ((size_t)bh << 14);
#pragma unroll
  for (int p = 0; p < 16; ++p) {
    const int idx = t + p * 256;
    const float4 v = *(const float4*)(Mg + (size_t)idx * 4);
    bf16_t* d = &((bf16_t*)Ms)[idx * 4];
    d[0] = (bf16_t)v.x; d[1] = (bf16_t)v.y; d[2] = (bf16_t)v.z; d[3] = (bf16_t)v.w;
  }
  __syncthreads();
  const int tr = t >> 4, tc = t & 15;
  float acc[4][8] = {};
  for (int e = 0; e < 128; ++e) {
    float q[4];
#pragma unroll
    for (int i = 0; i < 4; ++i)
      q[i] = (float)((const bf16_t*)Qs)[(tr * 4 + i) * 128 + e];
    const bf16x8 m8 = *(const bf16x8*)&Ms[e * 128 + tc * 8];
    float mf[8];
#pragma unroll
    for (int j = 0; j < 8; ++j) mf[j] = (float)m8[j];
#pragma unroll
    for (int i = 0; i < 4; ++i)
#pragma unroll
      for (int j = 0; j < 8; ++j) acc[i][j] += q[i] * mf[j];
  }
#pragma unroll
  for (int i = 0; i < 4; ++i) {
    const int n = n0 + tr * 4 + i;
#pragma unroll
    for (int j = 0; j < 8; ++j)
      O[(size_t)(b * 2048 + n) * 1024 + h * 128 + tc * 8 + j] = (bf16_t)acc[i][j];
  }
}

// ---------------------------------------------------------------------------
// ws layout (needs 40 MB + 32 KB; R5/R7 proved ws_size >= this):
//   RegionA [0,14M):  xb 8M + wqkvb 6M  ->  Mpart 4M @0 | M 1M @4M | O 8M @5M
//   wob   @14M (2M)
//   slabs @16M (24M)  q:0-15 k:16-31 v:32-47
//   flags @40M (int[8]) | bqf fp32 @40M+4K | bof fp32 @40M+20K
// ---------------------------------------------------------------------------
extern "C" void kernel_launch(void* const* d_in, const int* in_sizes, int n_in,
                              void* d_out, int out_size, void* d_ws, size_t ws_size,
                              hipStream_t stream) {
  float* out = (float*)d_out;        // FP32 output (round-8 probe)
  dim3 blk(256);

  int ix = -1, iwq = -1, ibq = -1, iwo = -1, ibo = -1;
  if (n_in == 5) {
    for (int i = 0; i < 5; ++i) {
      switch (in_sizes[i]) {
        case 4194304: ix  = i; break;
        case 3145728: iwq = i; break;
        case 3072:    ibq = i; break;
        case 1048576: iwo = i; break;
        case 1024:    ibo = i; break;
        default: break;
      }
    }
  }
  if (ix < 0 || iwq < 0 || ibq < 0 || iwo < 0 || ibo < 0) {
    beacon_kernel<<<dim3((out_size + 255) / 256), blk, 0, stream>>>(out, 50000.0f, out_size);
    return;
  }
  const size_t NEEDED = (size_t)40 * 1048576 + 32768;
  if (ws_size < NEEDED) {
    beacon_kernel<<<dim3((out_size + 255) / 256), blk, 0, stream>>>(out, 30000.0f, out_size);
    return;
  }

  char* ws = (char*)d_ws;
  bf16_t* xb    = (bf16_t*)(ws);
  bf16_t* wqkvb = (bf16_t*)(ws + (size_t)8  * 1048576);
  float*  Mpart = (float*) (ws);
  float*  M     = (float*) (ws + (size_t)4  * 1048576);
  bf16_t* O     = (bf16_t*)(ws + (size_t)5  * 1048576);
  bf16_t* wob   = (bf16_t*)(ws + (size_t)14 * 1048576);
  bf16_t* slabs = (bf16_t*)(ws + (size_t)16 * 1048576);
  int*    flags = (int*)   (ws + (size_t)40 * 1048576);
  float*  bqf   = (float*) (ws + (size_t)40 * 1048576 + 4096);
  float*  bof   = (float*) (ws + (size_t)40 * 1048576 + 20480);

  init_flags_kernel<<<1, dim3(64), 0, stream>>>(flags);
  // biases: copy fp32 -> fp32 staging (zeros per setup, but stay faithful)
  conv_kernel<<<4096, blk, 0, stream>>>((const float*)d_in[ix],  xb,    1048576);
  conv_kernel<<<3072, blk, 0, stream>>>((const float*)d_in[iwq], wqkvb, 786432);
  conv_kernel<<<1024, blk, 0, stream>>>((const float*)d_in[iwo], wob,   262144);
  hipMemcpyAsync(bqf, d_in[ibq], 3072 * sizeof(float), hipMemcpyDeviceToDevice, stream);
  hipMemcpyAsync(bof, d_in[ibo], 1024 * sizeof(float), hipMemcpyDeviceToDevice, stream);

  mfma_gemm_kernel<<<dim3(24, 32), blk, 0, stream>>>(xb, wqkvb, bqf, slabs, out, 0);
  chk1_kernel     <<<2,            blk, 0, stream>>>(xb, wqkvb, bqf, slabs, flags + 0);
  vec_gemm_kernel <<<dim3(24, 32), blk, 0, stream>>>(xb, wqkvb, bqf, slabs, out, 0, flags + 0);

  kv_part <<<dim3(4, 16),  blk, 0, stream>>>(slabs, Mpart);
  reduce_m<<<dim3(1024),   blk, 0, stream>>>(Mpart, M);
  qm      <<<dim3(32, 16), blk, 0, stream>>>(slabs, M, O);

  mfma_gemm_kernel<<<dim3(8, 32), blk, 0, stream>>>(O, wob, bof, slabs, out, 1);
  chk2_kernel     <<<1,           blk, 0, stream>>>(O, wob, bof, out, flags + 1);
  vec_gemm_kernel <<<dim3(8, 32), blk, 0, stream>>>(O, wob, bof, slabs, out, 1, flags + 1);
}

// Round 10
// 225.805 us; speedup vs baseline: 1.6489x; 1.6489x over previous
//
#include <hip/hip_runtime.h>
#include <hip/hip_bf16.h>
#include <stdint.h>

// B=2, N=2048, D=1024, H=8, DH=128. Inputs fp32, OUTPUT fp32 (R8 probe).
// qkv col = kk*1024 + dd*8 + hh (head innermost, displayed reference).
// No softmax => Q(K^T V). Pipeline:
//   conv_xw -> gemm1 (row-major qkv, coalesced) -> deint (LDS transpose ->
//   Q/K/V slabs) -> conv_wo -> kv_part -> reduce_m -> qm -> gemm2 (fp32 out)
// ws (40 MB, proven safe) lifetime map:
//   [0,8M)   xb          -> Q slabs      (after gemm1)
//   [8,14M)  wqkvb       -> Mpart 4M @8M + M 1M @12M (after gemm1)
//   [16,40M) qkv_rm 24M  -> O 8M @16M + wob 2M @24M  (after deint)
//   K slabs = d_out[0,8M), V slabs = d_out[8,16M) (d_out dead until gemm2)

typedef __bf16 bf16_t;
typedef __bf16 bf16x4 __attribute__((ext_vector_type(4)));
typedef __bf16 bf16x8 __attribute__((ext_vector_type(8)));
typedef float  fx4    __attribute__((ext_vector_type(4)));
typedef unsigned short u16;
typedef u16 u16x4 __attribute__((ext_vector_type(4)));
typedef u16 u16x8 __attribute__((ext_vector_type(8)));

typedef const void __attribute__((address_space(1)))* gas_ptr;
typedef void __attribute__((address_space(3)))*       las_ptr;

__device__ __forceinline__ void gl_lds16(const void* g, void* l) {
  __builtin_amdgcn_global_load_lds((gas_ptr)g, (las_ptr)l, 16, 0, 0);
}

#define SLAB 262144   // 2048*128 elems per (b,h) slab

// ---------------------------------------------------------------------------
__global__ __launch_bounds__(256) void beacon_kernel(float* out, float val, int n)
{
  const int i = blockIdx.x * 256 + threadIdx.x;
  if (i < n) out[i] = val;
}

// fp32 -> bf16 for x (1048576 float4) + w_qkv (786432 float4), one launch
__global__ __launch_bounds__(256) void conv_xw_kernel(
    const float* __restrict__ x, const float* __restrict__ wq,
    bf16_t* __restrict__ xb, bf16_t* __restrict__ wqkvb)
{
  const int i = blockIdx.x * 256 + threadIdx.x;   // < 1835008
  const float* src; bf16_t* dst; int off;
  if (i < 1048576) { src = x;  dst = xb;    off = i; }
  else             { src = wq; dst = wqkvb; off = i - 1048576; }
  const float4 v = ((const float4*)src)[off];
  bf16x4 o;
  o[0] = (bf16_t)v.x; o[1] = (bf16_t)v.y; o[2] = (bf16_t)v.z; o[3] = (bf16_t)v.w;
  ((bf16x4*)dst)[off] = o;
}

__global__ __launch_bounds__(256) void conv_wo_kernel(
    const float* __restrict__ wo, bf16_t* __restrict__ wob)
{
  const int i = blockIdx.x * 256 + threadIdx.x;   // < 262144
  const float4 v = ((const float4*)wo)[i];
  bf16x4 o;
  o[0] = (bf16_t)v.x; o[1] = (bf16_t)v.y; o[2] = (bf16_t)v.z; o[3] = (bf16_t)v.w;
  ((bf16x4*)wob)[i] = o;
}

// ---------------------------------------------------------------------------
// MFMA GEMM (m97): C[M,N] = A[M,1024] @ Bt[N,1024]^T + bias.
// mode 0: bf16 row-major out, ldc=3072 (qkv).  mode 1: fp32 out, ldc=1024.
// ---------------------------------------------------------------------------
__global__ __launch_bounds__(256) void mfma_gemm_kernel(
    const bf16_t* __restrict__ A, const bf16_t* __restrict__ Bt,
    const float* __restrict__ bias, bf16_t* __restrict__ outb,
    float* __restrict__ outf, int ldc, int mode)
{
  __shared__ __align__(16) short As[128*32];
  __shared__ __align__(16) short Bs[128*32];
  const int t    = threadIdx.x;
  const int lane = t & 63;
  const int w    = t >> 6;
  const int wr   = (w >> 1) << 6;
  const int wc   = (w & 1) << 6;
  const int lrow = lane & 15;
  const int kq   = (lane >> 4) << 3;
  const int row0 = blockIdx.y * 128;
  const int col0 = blockIdx.x * 128;

  const int i0 = t, i1 = t + 256;
  const bf16_t* a0 = A  + (size_t)(row0 + (i0 >> 2)) * 1024 + ((i0 & 3) << 3);
  const bf16_t* a1 = A  + (size_t)(row0 + (i1 >> 2)) * 1024 + ((i1 & 3) << 3);
  const bf16_t* b0 = Bt + (size_t)(col0 + (i0 >> 2)) * 1024 + ((i0 & 3) << 3);
  const bf16_t* b1 = Bt + (size_t)(col0 + (i1 >> 2)) * 1024 + ((i1 & 3) << 3);
  short* sa0 = &As[i0 * 8]; short* sa1 = &As[i1 * 8];
  short* sb0 = &Bs[i0 * 8]; short* sb1 = &Bs[i1 * 8];

  fx4 acc[4][4] = {};

  for (int k0 = 0; k0 < 1024; k0 += 32) {
    gl_lds16(a0 + k0, sa0);
    gl_lds16(a1 + k0, sa1);
    gl_lds16(b0 + k0, sb0);
    gl_lds16(b1 + k0, sb1);
    __syncthreads();
    bf16x8 af[4], bfr[4];
#pragma unroll
    for (int i = 0; i < 4; ++i)
      af[i] = *(const bf16x8*)&As[(wr + i*16 + lrow)*32 + kq];
#pragma unroll
    for (int j = 0; j < 4; ++j)
      bfr[j] = *(const bf16x8*)&Bs[(wc + j*16 + lrow)*32 + kq];
#pragma unroll
    for (int i = 0; i < 4; ++i)
#pragma unroll
      for (int j = 0; j < 4; ++j)
        acc[i][j] = __builtin_amdgcn_mfma_f32_16x16x32_bf16(af[i], bfr[j], acc[i][j], 0, 0, 0);
    __syncthreads();
  }

  // C/D: col = lane&15, row = (lane>>4)*4 + reg  [m89-verified]
#pragma unroll
  for (int j = 0; j < 4; ++j) {
    const int col = col0 + wc + j*16 + lrow;
    const float bv = bias[col];
#pragma unroll
    for (int i = 0; i < 4; ++i) {
#pragma unroll
      for (int r = 0; r < 4; ++r) {
        const int row = row0 + wr + i*16 + ((lane >> 4) << 2) + r;
        const float v = acc[i][j][r] + bv;
        if (mode == 0) outb[(size_t)row * ldc + col] = (bf16_t)v;
        else           outf[(size_t)row * ldc + col] = v;
      }
    }
  }
}

// ---------------------------------------------------------------------------
// Deinterleave: qkv_rm[4096][3072] -> slabs [b*8+hh][n][dd] per kk.
// Block = (kk, 16-row tile). In: u16x8 = one dd x 8 hh -> 8 ds_write_b64.
// Out: contiguous slab rows via 2x ds_read_b64 + u16x8 global store.
// ---------------------------------------------------------------------------
__global__ __launch_bounds__(256) void deint_kernel(
    const bf16_t* __restrict__ qkv, bf16_t* __restrict__ Qb,
    bf16_t* __restrict__ Kb, bf16_t* __restrict__ Vb)
{
  __shared__ u16 L[8][16][132];   // 33 KB; +4 pad keeps banks spread
  const int t    = threadIdx.x;
  const int kk   = blockIdx.x;    // 0=q 1=k 2=v
  const int tile = blockIdx.y;    // 0..255
  const int gr0  = tile * 16;
  const u16* src_base = (const u16*)qkv + (size_t)gr0 * 3072 + kk * 1024;

#pragma unroll
  for (int p = 0; p < 2; ++p) {
    const int task = t + p * 256;            // 512 tasks: 16 r x 32 g
    const int r = task >> 5, g = task & 31;
    const u16x8* s = (const u16x8*)(src_base + (size_t)r * 3072 + 32 * g);
    const u16x8 u0 = s[0], u1 = s[1], u2 = s[2], u3 = s[3];
#pragma unroll
    for (int hh = 0; hh < 8; ++hh) {
      u16x4 wv = { u0[hh], u1[hh], u2[hh], u3[hh] };   // dd = 4g..4g+3
      *(u16x4*)&L[hh][r][4 * g] = wv;
    }
  }
  __syncthreads();

  const int b  = gr0 >> 11;
  const int n0 = gr0 & 2047;
  bf16_t* base = (kk == 0) ? Qb : (kk == 1 ? Kb : Vb);
#pragma unroll
  for (int p = 0; p < 8; ++p) {
    const int task = t + p * 256;            // 2048 tasks: 8 hh x 16 r x 16 q
    const int hh = task >> 8, rem = task & 255;
    const int r = rem >> 4, q = rem & 15;
    const u16x4 w0 = *(const u16x4*)&L[hh][r][8 * q];
    const u16x4 w1 = *(const u16x4*)&L[hh][r][8 * q + 4];
    u16x8 wv = { w0[0], w0[1], w0[2], w0[3], w1[0], w1[1], w1[2], w1[3] };
    *(u16x8*)(base + (size_t)(b * 8 + hh) * SLAB + (size_t)(n0 + r) * 128 + 8 * q) = wv;
  }
}

// ---------------------------------------------------------------------------
// Mpart[bh][ch][e][d] = sum_{n in 512-chunk} K[n][e] * V[n][d]
// grid (8 = 4 ch x 2 d-half, 16 bh): 128 blocks.
__global__ __launch_bounds__(256) void kv_part(
    const bf16_t* __restrict__ Kb, const bf16_t* __restrict__ Vb,
    float* __restrict__ Mpart)
{
  __shared__ short Ks[64 * 128];
  __shared__ short Vs[64 * 64];
  const int t = threadIdx.x;
  const int ch = blockIdx.x >> 1, dh = blockIdx.x & 1, bh = blockIdx.y;
  const bf16_t* Kg = Kb + (size_t)bh * SLAB;
  const bf16_t* Vg = Vb + (size_t)bh * SLAB + dh * 64;
  const int e0 = (t >> 4) * 8, d0 = (t & 15) * 4;
  float acc[8][4] = {};
  for (int sub = 0; sub < 8; ++sub) {
    const int n0 = ch * 512 + sub * 64;
#pragma unroll
    for (int p = 0; p < 4; ++p) {
      const int idx = t + p * 256;           // 1024 u16x8 groups for K
      const int r = idx >> 4, c = (idx & 15) * 8;
      *(uint4*)&Ks[idx * 8] = *(const uint4*)(Kg + (size_t)(n0 + r) * 128 + c);
    }
#pragma unroll
    for (int p = 0; p < 2; ++p) {
      const int idx = t + p * 256;           // 512 groups for V half
      const int r = idx >> 3, c = (idx & 7) * 8;
      *(uint4*)&Vs[idx * 8] = *(const uint4*)(Vg + (size_t)(n0 + r) * 128 + c);
    }
    __syncthreads();
    for (int n = 0; n < 64; ++n) {
      const bf16x8 k8 = *(const bf16x8*)&Ks[n * 128 + e0];
      const bf16x4 v4 = *(const bf16x4*)&Vs[n * 64 + d0];
      float kf[8], vf[4];
#pragma unroll
      for (int i = 0; i < 8; ++i) kf[i] = (float)k8[i];
#pragma unroll
      for (int j = 0; j < 4; ++j) vf[j] = (float)v4[j];
#pragma unroll
      for (int i = 0; i < 8; ++i)
#pragma unroll
        for (int j = 0; j < 4; ++j) acc[i][j] += kf[i] * vf[j];
    }
    __syncthreads();
  }
  float* op = Mpart + ((size_t)(bh * 4 + ch) << 14) + dh * 64;
#pragma unroll
  for (int i = 0; i < 8; ++i)
#pragma unroll
    for (int j = 0; j < 4; ++j)
      op[(e0 + i) * 128 + d0 + j] = acc[i][j];
}

__global__ __launch_bounds__(256) void reduce_m(
    const float* __restrict__ Mpart, float* __restrict__ M)
{
  const int o = blockIdx.x * 256 + threadIdx.x;   // < 262144
  const int bh = o >> 14, rest = o & 16383;
  const float* p = Mpart + ((size_t)(bh * 4) << 14) + rest;
  M[o] = p[0] + p[16384] + p[32768] + p[49152];
}

// O[b*2048+n][h*128+d] = sum_e Q[n][e] * M[bh][e][d]
__global__ __launch_bounds__(256) void qm(
    const bf16_t* __restrict__ Qb, const float* __restrict__ M,
    bf16_t* __restrict__ O)
{
  __shared__ short Qs[64 * 128];
  __shared__ short Ms[128 * 128];
  const int t = threadIdx.x;
  const int bh = blockIdx.y, n0 = blockIdx.x * 64;
  const int b = bh >> 3, h = bh & 7;
  const bf16_t* Qg = Qb + (size_t)bh * SLAB + (size_t)n0 * 128;
#pragma unroll
  for (int p = 0; p < 4; ++p) {
    const int idx = t + p * 256;
    *(uint4*)&Qs[idx * 8] = *(const uint4*)(Qg + (size_t)idx * 8);
  }
  const float* Mg = M + ((size_t)bh << 14);
#pragma unroll
  for (int p = 0; p < 16; ++p) {
    const int idx = t + p * 256;
    const float4 v = *(const float4*)(Mg + (size_t)idx * 4);
    bf16_t* d = &((bf16_t*)Ms)[idx * 4];
    d[0] = (bf16_t)v.x; d[1] = (bf16_t)v.y; d[2] = (bf16_t)v.z; d[3] = (bf16_t)v.w;
  }
  __syncthreads();
  const int tr = t >> 4, tc = t & 15;
  float acc[4][8] = {};
  for (int e = 0; e < 128; ++e) {
    float q[4];
#pragma unroll
    for (int i = 0; i < 4; ++i)
      q[i] = (float)((const bf16_t*)Qs)[(tr * 4 + i) * 128 + e];
    const bf16x8 m8 = *(const bf16x8*)&Ms[e * 128 + tc * 8];
    float mf[8];
#pragma unroll
    for (int j = 0; j < 8; ++j) mf[j] = (float)m8[j];
#pragma unroll
    for (int i = 0; i < 4; ++i)
#pragma unroll
      for (int j = 0; j < 8; ++j) acc[i][j] += q[i] * mf[j];
  }
#pragma unroll
  for (int i = 0; i < 4; ++i) {
    const int n = n0 + tr * 4 + i;
#pragma unroll
    for (int j = 0; j < 8; ++j)
      O[(size_t)(b * 2048 + n) * 1024 + h * 128 + tc * 8 + j] = (bf16_t)acc[i][j];
  }
}

// ---------------------------------------------------------------------------
extern "C" void kernel_launch(void* const* d_in, const int* in_sizes, int n_in,
                              void* d_out, int out_size, void* d_ws, size_t ws_size,
                              hipStream_t stream) {
  float* out = (float*)d_out;
  dim3 blk(256);

  int ix = -1, iwq = -1, ibq = -1, iwo = -1, ibo = -1;
  if (n_in == 5) {
    for (int i = 0; i < 5; ++i) {
      switch (in_sizes[i]) {
        case 4194304: ix  = i; break;
        case 3145728: iwq = i; break;
        case 3072:    ibq = i; break;
        case 1048576: iwo = i; break;
        case 1024:    ibo = i; break;
        default: break;
      }
    }
  }
  if (ix < 0 || iwq < 0 || ibq < 0 || iwo < 0 || ibo < 0) {
    beacon_kernel<<<dim3((out_size + 255) / 256), blk, 0, stream>>>(out, 50000.0f, out_size);
    return;
  }
  const size_t NEEDED = (size_t)40 * 1048576;
  if (ws_size < NEEDED) {
    beacon_kernel<<<dim3((out_size + 255) / 256), blk, 0, stream>>>(out, 30000.0f, out_size);
    return;
  }

  char* ws = (char*)d_ws;
  bf16_t* xb     = (bf16_t*)(ws);                          // [0,8M)
  bf16_t* Qb     = (bf16_t*)(ws);                          // [0,8M)  after gemm1
  bf16_t* wqkvb  = (bf16_t*)(ws + (size_t)8  * 1048576);   // [8,14M)
  float*  Mpart  = (float*) (ws + (size_t)8  * 1048576);   // [8,12M) after gemm1
  float*  M      = (float*) (ws + (size_t)12 * 1048576);   // [12,13M)
  bf16_t* qkv_rm = (bf16_t*)(ws + (size_t)16 * 1048576);   // [16,40M)
  bf16_t* O      = (bf16_t*)(ws + (size_t)16 * 1048576);   // [16,24M) after deint
  bf16_t* wob    = (bf16_t*)(ws + (size_t)24 * 1048576);   // [24,26M) after deint
  bf16_t* Kb     = (bf16_t*)d_out;                         // d_out[0,8M)
  bf16_t* Vb     = (bf16_t*)d_out + 16 * SLAB;             // d_out[8,16M)

  const float* bq = (const float*)d_in[ibq];
  const float* bo = (const float*)d_in[ibo];

  conv_xw_kernel <<<dim3(7168),    blk, 0, stream>>>((const float*)d_in[ix],
                                                     (const float*)d_in[iwq], xb, wqkvb);
  mfma_gemm_kernel<<<dim3(24, 32), blk, 0, stream>>>(xb, wqkvb, bq, qkv_rm, out, 3072, 0);
  deint_kernel   <<<dim3(3, 256),  blk, 0, stream>>>(qkv_rm, Qb, Kb, Vb);
  conv_wo_kernel <<<dim3(1024),    blk, 0, stream>>>((const float*)d_in[iwo], wob);
  kv_part        <<<dim3(8, 16),   blk, 0, stream>>>(Kb, Vb, Mpart);
  reduce_m       <<<dim3(1024),    blk, 0, stream>>>(Mpart, M);
  qm             <<<dim3(32, 16),  blk, 0, stream>>>(Qb, M, O);
  mfma_gemm_kernel<<<dim3(8, 32),  blk, 0, stream>>>(O, wob, bo, qkv_rm, out, 1024, 1);
}

// Round 11
// 187.647 us; speedup vs baseline: 1.9842x; 1.2033x over previous
//
#include <hip/hip_runtime.h>
#include <hip/hip_bf16.h>
#include <stdint.h>

// B=2, N=2048, D=1024, H=8, DH=128. Inputs fp32, OUTPUT fp32.
// qkv col = kk*1024 + dd*8 + hh (head innermost). No softmax => Q(K^T V).
// Pipeline: conv_xw -> gemm1 (row-major qkv) -> deint (Q/K/V slabs) ->
//   conv_wo -> kv_part (vector, fp32-LDS) -> reduce_mt (sum + transpose ->
//   Mt bf16) -> qm_mfma (O = Q*M via MFMA) -> gemm2 (fp32 out).
// ws map (40 MB proven):
//   [0,8M)   xb -> Qb (after gemm1/deint)
//   [8,14M)  wqkvb -> O @[8,16M) (after gemm1)
//   [16,40M) qkv_rm -> Mpart 16M @16M, Mt 0.5M @32M, wob 2M @33M (after deint)
//   Kb = d_out[0,8M), Vb = d_out[8,16M)  (d_out dead until gemm2)

typedef __bf16 bf16_t;
typedef __bf16 bf16x4 __attribute__((ext_vector_type(4)));
typedef __bf16 bf16x8 __attribute__((ext_vector_type(8)));
typedef float  fx4    __attribute__((ext_vector_type(4)));
typedef unsigned short u16;
typedef u16 u16x4 __attribute__((ext_vector_type(4)));
typedef u16 u16x8 __attribute__((ext_vector_type(8)));

typedef const void __attribute__((address_space(1)))* gas_ptr;
typedef void __attribute__((address_space(3)))*       las_ptr;

__device__ __forceinline__ void gl_lds16(const void* g, void* l) {
  __builtin_amdgcn_global_load_lds((gas_ptr)g, (las_ptr)l, 16, 0, 0);
}

#define SLAB 262144   // 2048*128 elems per (b,h) slab

// ---------------------------------------------------------------------------
__global__ __launch_bounds__(256) void beacon_kernel(float* out, float val, int n)
{
  const int i = blockIdx.x * 256 + threadIdx.x;
  if (i < n) out[i] = val;
}

__global__ __launch_bounds__(256) void conv_xw_kernel(
    const float* __restrict__ x, const float* __restrict__ wq,
    bf16_t* __restrict__ xb, bf16_t* __restrict__ wqkvb)
{
  const int i = blockIdx.x * 256 + threadIdx.x;   // < 1835008
  const float* src; bf16_t* dst; int off;
  if (i < 1048576) { src = x;  dst = xb;    off = i; }
  else             { src = wq; dst = wqkvb; off = i - 1048576; }
  const float4 v = ((const float4*)src)[off];
  bf16x4 o;
  o[0] = (bf16_t)v.x; o[1] = (bf16_t)v.y; o[2] = (bf16_t)v.z; o[3] = (bf16_t)v.w;
  ((bf16x4*)dst)[off] = o;
}

__global__ __launch_bounds__(256) void conv_wo_kernel(
    const float* __restrict__ wo, bf16_t* __restrict__ wob)
{
  const int i = blockIdx.x * 256 + threadIdx.x;   // < 262144
  const float4 v = ((const float4*)wo)[i];
  bf16x4 o;
  o[0] = (bf16_t)v.x; o[1] = (bf16_t)v.y; o[2] = (bf16_t)v.z; o[3] = (bf16_t)v.w;
  ((bf16x4*)wob)[i] = o;
}

// ---------------------------------------------------------------------------
// MFMA GEMM (m97): C[M,N] = A[M,1024] @ Bt[N,1024]^T + bias.
// mode 0: bf16 row-major out ldc (qkv).  mode 1: fp32 out ldc.
__global__ __launch_bounds__(256) void mfma_gemm_kernel(
    const bf16_t* __restrict__ A, const bf16_t* __restrict__ Bt,
    const float* __restrict__ bias, bf16_t* __restrict__ outb,
    float* __restrict__ outf, int ldc, int mode)
{
  __shared__ __align__(16) short As[128*32];
  __shared__ __align__(16) short Bs[128*32];
  const int t    = threadIdx.x;
  const int lane = t & 63;
  const int w    = t >> 6;
  const int wr   = (w >> 1) << 6;
  const int wc   = (w & 1) << 6;
  const int lrow = lane & 15;
  const int kq   = (lane >> 4) << 3;
  const int row0 = blockIdx.y * 128;
  const int col0 = blockIdx.x * 128;

  const int i0 = t, i1 = t + 256;
  const bf16_t* a0 = A  + (size_t)(row0 + (i0 >> 2)) * 1024 + ((i0 & 3) << 3);
  const bf16_t* a1 = A  + (size_t)(row0 + (i1 >> 2)) * 1024 + ((i1 & 3) << 3);
  const bf16_t* b0 = Bt + (size_t)(col0 + (i0 >> 2)) * 1024 + ((i0 & 3) << 3);
  const bf16_t* b1 = Bt + (size_t)(col0 + (i1 >> 2)) * 1024 + ((i1 & 3) << 3);
  short* sa0 = &As[i0 * 8]; short* sa1 = &As[i1 * 8];
  short* sb0 = &Bs[i0 * 8]; short* sb1 = &Bs[i1 * 8];

  fx4 acc[4][4] = {};

  for (int k0 = 0; k0 < 1024; k0 += 32) {
    gl_lds16(a0 + k0, sa0);
    gl_lds16(a1 + k0, sa1);
    gl_lds16(b0 + k0, sb0);
    gl_lds16(b1 + k0, sb1);
    __syncthreads();
    bf16x8 af[4], bfr[4];
#pragma unroll
    for (int i = 0; i < 4; ++i)
      af[i] = *(const bf16x8*)&As[(wr + i*16 + lrow)*32 + kq];
#pragma unroll
    for (int j = 0; j < 4; ++j)
      bfr[j] = *(const bf16x8*)&Bs[(wc + j*16 + lrow)*32 + kq];
#pragma unroll
    for (int i = 0; i < 4; ++i)
#pragma unroll
      for (int j = 0; j < 4; ++j)
        acc[i][j] = __builtin_amdgcn_mfma_f32_16x16x32_bf16(af[i], bfr[j], acc[i][j], 0, 0, 0);
    __syncthreads();
  }

#pragma unroll
  for (int j = 0; j < 4; ++j) {
    const int col = col0 + wc + j*16 + lrow;
    const float bv = bias[col];
#pragma unroll
    for (int i = 0; i < 4; ++i) {
#pragma unroll
      for (int r = 0; r < 4; ++r) {
        const int row = row0 + wr + i*16 + ((lane >> 4) << 2) + r;
        const float v = acc[i][j][r] + bv;
        if (mode == 0) outb[(size_t)row * ldc + col] = (bf16_t)v;
        else           outf[(size_t)row * ldc + col] = v;
      }
    }
  }
}

// ---------------------------------------------------------------------------
// Deinterleave: qkv_rm[4096][3072] -> slabs [b*8+hh][n][dd] per kk.
__global__ __launch_bounds__(256) void deint_kernel(
    const bf16_t* __restrict__ qkv, bf16_t* __restrict__ Qb,
    bf16_t* __restrict__ Kb, bf16_t* __restrict__ Vb)
{
  __shared__ u16 L[8][16][132];
  const int t    = threadIdx.x;
  const int kk   = blockIdx.x;    // 0=q 1=k 2=v
  const int tile = blockIdx.y;    // 0..255
  const int gr0  = tile * 16;
  const u16* src_base = (const u16*)qkv + (size_t)gr0 * 3072 + kk * 1024;

#pragma unroll
  for (int p = 0; p < 2; ++p) {
    const int task = t + p * 256;
    const int r = task >> 5, g = task & 31;
    const u16x8* s = (const u16x8*)(src_base + (size_t)r * 3072 + 32 * g);
    const u16x8 u0 = s[0], u1 = s[1], u2 = s[2], u3 = s[3];
#pragma unroll
    for (int hh = 0; hh < 8; ++hh) {
      u16x4 wv = { u0[hh], u1[hh], u2[hh], u3[hh] };
      *(u16x4*)&L[hh][r][4 * g] = wv;
    }
  }
  __syncthreads();

  const int b  = gr0 >> 11;
  const int n0 = gr0 & 2047;
  bf16_t* base = (kk == 0) ? Qb : (kk == 1 ? Kb : Vb);
#pragma unroll
  for (int p = 0; p < 8; ++p) {
    const int task = t + p * 256;
    const int hh = task >> 8, rem = task & 255;
    const int r = rem >> 4, q = rem & 15;
    const u16x4 w0 = *(const u16x4*)&L[hh][r][8 * q];
    const u16x4 w1 = *(const u16x4*)&L[hh][r][8 * q + 4];
    u16x8 wv = { w0[0], w0[1], w0[2], w0[3], w1[0], w1[1], w1[2], w1[3] };
    *(u16x8*)(base + (size_t)(b * 8 + hh) * SLAB + (size_t)(n0 + r) * 128 + 8 * q) = wv;
  }
}

// ---------------------------------------------------------------------------
// kv_part v2: Mpart[bh][ch][e][d] += K[n][e]*V[n][d] over n in 128-chunk.
// grid (32 = 16 ch x 2 dhalf, 16 bh) = 512 blocks. fp32 LDS (cvt once).
__global__ __launch_bounds__(256) void kv_part(
    const bf16_t* __restrict__ Kb, const bf16_t* __restrict__ Vb,
    float* __restrict__ Mpart)
{
  __shared__ float Ksf[64][128];   // 32 KB
  __shared__ float Vsf[64][64];    // 16 KB
  const int t = threadIdx.x;
  const int ch = blockIdx.x >> 1, dh = blockIdx.x & 1, bh = blockIdx.y;
  const bf16_t* Kg = Kb + (size_t)bh * SLAB;
  const bf16_t* Vg = Vb + (size_t)bh * SLAB + dh * 64;
  const int e0 = (t >> 4) * 8, d0 = (t & 15) * 4;
  float acc[8][4] = {};

  for (int sub = 0; sub < 2; ++sub) {
    const int n0 = ch * 128 + sub * 64;
#pragma unroll
    for (int p = 0; p < 4; ++p) {           // K: 1024 groups of 8
      const int idx = t + p * 256;
      const int r = idx >> 4, c = (idx & 15) * 8;
      const bf16x8 k8 = *(const bf16x8*)(Kg + (size_t)(n0 + r) * 128 + c);
      float4 f0 = { (float)k8[0], (float)k8[1], (float)k8[2], (float)k8[3] };
      float4 f1 = { (float)k8[4], (float)k8[5], (float)k8[6], (float)k8[7] };
      *(float4*)&Ksf[r][c]     = f0;
      *(float4*)&Ksf[r][c + 4] = f1;
    }
#pragma unroll
    for (int p = 0; p < 2; ++p) {           // V: 512 groups of 8
      const int idx = t + p * 256;
      const int r = idx >> 3, c = (idx & 7) * 8;
      const bf16x8 v8 = *(const bf16x8*)(Vg + (size_t)(n0 + r) * 128 + c);
      float4 f0 = { (float)v8[0], (float)v8[1], (float)v8[2], (float)v8[3] };
      float4 f1 = { (float)v8[4], (float)v8[5], (float)v8[6], (float)v8[7] };
      *(float4*)&Vsf[r][c]     = f0;
      *(float4*)&Vsf[r][c + 4] = f1;
    }
    __syncthreads();
    for (int n = 0; n < 64; ++n) {
      const float4 ka = *(const float4*)&Ksf[n][e0];
      const float4 kb = *(const float4*)&Ksf[n][e0 + 4];
      const float4 vv = *(const float4*)&Vsf[n][d0];
      const float kf[8] = { ka.x, ka.y, ka.z, ka.w, kb.x, kb.y, kb.z, kb.w };
      const float vf[4] = { vv.x, vv.y, vv.z, vv.w };
#pragma unroll
      for (int i = 0; i < 8; ++i)
#pragma unroll
        for (int j = 0; j < 4; ++j) acc[i][j] += kf[i] * vf[j];
    }
    __syncthreads();
  }

  float* op = Mpart + ((size_t)(bh * 16 + ch) << 14) + dh * 64;
#pragma unroll
  for (int i = 0; i < 8; ++i)
    *(float4*)&op[(e0 + i) * 128 + d0] = *(const float4*)&acc[i][0];
}

// ---------------------------------------------------------------------------
// reduce_mt: Mt[bh][d][e] (bf16) = sum_{ch<16} Mpart[bh][ch][e][d]
// grid (8, 16); coalesced fp32 reads (lanes along d), u16x8 transposed write.
__global__ __launch_bounds__(256) void reduce_mt(
    const float* __restrict__ Mpart, bf16_t* __restrict__ Mt)
{
  const int t = threadIdx.x, bh = blockIdx.y;
  const int task = blockIdx.x * 256 + t;    // 0..2047
  const int eo = task >> 7, d = task & 127;
  const float* base = Mpart + ((size_t)(bh * 16) << 14) + d;
  float s[8] = {};
#pragma unroll
  for (int ch = 0; ch < 16; ++ch) {
    const float* p = base + ((size_t)ch << 14) + (eo * 8) * 128;
#pragma unroll
    for (int j = 0; j < 8; ++j) s[j] += p[j * 128];
  }
  u16x8 wv;
#pragma unroll
  for (int j = 0; j < 8; ++j) { bf16_t b = (bf16_t)s[j]; wv[j] = *(u16*)&b; }
  *(u16x8*)(Mt + (size_t)bh * 16384 + (size_t)d * 128 + eo * 8) = wv;
}

// ---------------------------------------------------------------------------
// qm_mfma: O[b*2048+n][h*128+d] = sum_e Q[n][e] * M[e][d], per bh.
// A = Qb slab rows [n][e]; B-operand = Mt rows [d][e]; K=128.
// grid (16 ntiles, 16 bh).
__global__ __launch_bounds__(256) void qm_mfma_kernel(
    const bf16_t* __restrict__ Qb, const bf16_t* __restrict__ Mt,
    bf16_t* __restrict__ O)
{
  __shared__ __align__(16) short As[128*32];
  __shared__ __align__(16) short Bs[128*32];
  const int t    = threadIdx.x;
  const int lane = t & 63;
  const int w    = t >> 6;
  const int wr   = (w >> 1) << 6;
  const int wc   = (w & 1) << 6;
  const int lrow = lane & 15;
  const int kq   = (lane >> 4) << 3;
  const int row0 = blockIdx.x * 128;
  const int bh   = blockIdx.y;
  const bf16_t* A  = Qb + (size_t)bh * SLAB;
  const bf16_t* Bt = Mt + (size_t)bh * 16384;

  const int i0 = t, i1 = t + 256;
  const bf16_t* a0 = A  + (size_t)(row0 + (i0 >> 2)) * 128 + ((i0 & 3) << 3);
  const bf16_t* a1 = A  + (size_t)(row0 + (i1 >> 2)) * 128 + ((i1 & 3) << 3);
  const bf16_t* b0 = Bt + (size_t)(i0 >> 2) * 128 + ((i0 & 3) << 3);
  const bf16_t* b1 = Bt + (size_t)(i1 >> 2) * 128 + ((i1 & 3) << 3);
  short* sa0 = &As[i0 * 8]; short* sa1 = &As[i1 * 8];
  short* sb0 = &Bs[i0 * 8]; short* sb1 = &Bs[i1 * 8];

  fx4 acc[4][4] = {};

  for (int k0 = 0; k0 < 128; k0 += 32) {
    gl_lds16(a0 + k0, sa0);
    gl_lds16(a1 + k0, sa1);
    gl_lds16(b0 + k0, sb0);
    gl_lds16(b1 + k0, sb1);
    __syncthreads();
    bf16x8 af[4], bfr[4];
#pragma unroll
    for (int i = 0; i < 4; ++i)
      af[i] = *(const bf16x8*)&As[(wr + i*16 + lrow)*32 + kq];
#pragma unroll
    for (int j = 0; j < 4; ++j)
      bfr[j] = *(const bf16x8*)&Bs[(wc + j*16 + lrow)*32 + kq];
#pragma unroll
    for (int i = 0; i < 4; ++i)
#pragma unroll
      for (int j = 0; j < 4; ++j)
        acc[i][j] = __builtin_amdgcn_mfma_f32_16x16x32_bf16(af[i], bfr[j], acc[i][j], 0, 0, 0);
    __syncthreads();
  }

  const int b = bh >> 3, h = bh & 7;
  bf16_t* obase = O + (size_t)(b * 2048) * 1024 + h * 128;
#pragma unroll
  for (int j = 0; j < 4; ++j) {
    const int col = wc + j*16 + lrow;          // d 0..127
#pragma unroll
    for (int i = 0; i < 4; ++i) {
#pragma unroll
      for (int r = 0; r < 4; ++r) {
        const int row = row0 + wr + i*16 + ((lane >> 4) << 2) + r;   // n
        obase[(size_t)row * 1024 + col] = (bf16_t)acc[i][j][r];
      }
    }
  }
}

// ---------------------------------------------------------------------------
extern "C" void kernel_launch(void* const* d_in, const int* in_sizes, int n_in,
                              void* d_out, int out_size, void* d_ws, size_t ws_size,
                              hipStream_t stream) {
  float* out = (float*)d_out;
  dim3 blk(256);

  int ix = -1, iwq = -1, ibq = -1, iwo = -1, ibo = -1;
  if (n_in == 5) {
    for (int i = 0; i < 5; ++i) {
      switch (in_sizes[i]) {
        case 4194304: ix  = i; break;
        case 3145728: iwq = i; break;
        case 3072:    ibq = i; break;
        case 1048576: iwo = i; break;
        case 1024:    ibo = i; break;
        default: break;
      }
    }
  }
  if (ix < 0 || iwq < 0 || ibq < 0 || iwo < 0 || ibo < 0) {
    beacon_kernel<<<dim3((out_size + 255) / 256), blk, 0, stream>>>(out, 50000.0f, out_size);
    return;
  }
  const size_t NEEDED = (size_t)40 * 1048576;
  if (ws_size < NEEDED) {
    beacon_kernel<<<dim3((out_size + 255) / 256), blk, 0, stream>>>(out, 30000.0f, out_size);
    return;
  }

  char* ws = (char*)d_ws;
  bf16_t* xb     = (bf16_t*)(ws);                          // [0,8M)
  bf16_t* Qb     = (bf16_t*)(ws);                          // [0,8M)  after gemm1
  bf16_t* wqkvb  = (bf16_t*)(ws + (size_t)8  * 1048576);   // [8,14M)
  bf16_t* O      = (bf16_t*)(ws + (size_t)8  * 1048576);   // [8,16M) after gemm1
  bf16_t* qkv_rm = (bf16_t*)(ws + (size_t)16 * 1048576);   // [16,40M)
  float*  Mpart  = (float*) (ws + (size_t)16 * 1048576);   // [16,32M) after deint
  bf16_t* Mt     = (bf16_t*)(ws + (size_t)32 * 1048576);   // [32,32.5M)
  bf16_t* wob    = (bf16_t*)(ws + (size_t)33 * 1048576);   // [33,35M) after deint
  bf16_t* Kb     = (bf16_t*)d_out;                         // d_out[0,8M)
  bf16_t* Vb     = (bf16_t*)d_out + 16 * SLAB;             // d_out[8,16M)

  const float* bq = (const float*)d_in[ibq];
  const float* bo = (const float*)d_in[ibo];

  conv_xw_kernel  <<<dim3(7168),    blk, 0, stream>>>((const float*)d_in[ix],
                                                      (const float*)d_in[iwq], xb, wqkvb);
  mfma_gemm_kernel<<<dim3(24, 32),  blk, 0, stream>>>(xb, wqkvb, bq, qkv_rm, out, 3072, 0);
  deint_kernel    <<<dim3(3, 256),  blk, 0, stream>>>(qkv_rm, Qb, Kb, Vb);
  conv_wo_kernel  <<<dim3(1024),    blk, 0, stream>>>((const float*)d_in[iwo], wob);
  kv_part         <<<dim3(32, 16),  blk, 0, stream>>>(Kb, Vb, Mpart);
  reduce_mt       <<<dim3(8, 16),   blk, 0, stream>>>(Mpart, Mt);
  qm_mfma_kernel  <<<dim3(16, 16),  blk, 0, stream>>>(Qb, Mt, O);
  mfma_gemm_kernel<<<dim3(8, 32),   blk, 0, stream>>>(O, wob, bo, qkv_rm, out, 1024, 1);
}